// Round 7
// baseline (389.730 us; speedup 1.0000x reference)
//
#include <hip/hip_runtime.h>

// Shapes fixed by setup_inputs(): B=4, L=1024, E=1024, H=16, D=64, W=128
#define BB 4
#define LL 1024
#define EE 1024
#define HH 16
#define DD 64

typedef __attribute__((ext_vector_type(8))) short short8;
typedef __attribute__((ext_vector_type(4))) float floatx4;

#define PSTR ((size_t)4096 * 1024)   // split-K partial stride (elements, bf16)

__device__ __forceinline__ float bf2f(short s) {
    union { unsigned u; float f; } c;
    c.u = ((unsigned)(unsigned short)s) << 16;
    return c.f;
}
__device__ __forceinline__ short f2bf(float f) {
    union { float f; unsigned u; } c; c.f = f;
    unsigned r = c.u + 0x7fffu + ((c.u >> 16) & 1u);
    return (short)(r >> 16);
}

__device__ __forceinline__ void async_copy16(const void* g, void* l) {
    __builtin_amdgcn_global_load_lds(
        (const __attribute__((address_space(1))) unsigned int*)g,
        (__attribute__((address_space(3))) unsigned int*)l, 16, 0, 0);
}

// ---------------------------------------------------------------- convert (all 5 tensors, one launch)
__global__ __launch_bounds__(256) void cvt5(
    const float* __restrict__ x, const float* __restrict__ wqkv,
    const float* __restrict__ wo, const float* __restrict__ w1,
    const float* __restrict__ w2,
    short* __restrict__ xb, short* __restrict__ wqkvb, short* __restrict__ wob,
    short* __restrict__ w1b, short* __restrict__ w2b)
{
    int bi = blockIdx.x;
    const float* in; short* out; int base;
    if      (bi <  4096) { in = x;    out = xb;    base = 0;     }
    else if (bi <  7168) { in = wqkv; out = wqkvb; base = 4096;  }
    else if (bi <  8192) { in = wo;   out = wob;   base = 7168;  }
    else if (bi < 12288) { in = w1;   out = w1b;   base = 8192;  }
    else                 { in = w2;   out = w2b;   base = 12288; }
    int i = (bi - base) * 256 + threadIdx.x;
    float4 v = ((const float4*)in)[i];
    unsigned long long u =
          (unsigned long long)(unsigned short)f2bf(v.x)
        | ((unsigned long long)(unsigned short)f2bf(v.y) << 16)
        | ((unsigned long long)(unsigned short)f2bf(v.z) << 32)
        | ((unsigned long long)(unsigned short)f2bf(v.w) << 48);
    ((unsigned long long*)out)[i] = u;
}

// ---------------------------------------------------------------- GEMM (NT)
// C[m,n] = sum_k A[m,k]*B[n,k] (+bias); 128x128 tile, BK=64, 256 thr.
// LDS k-chunk XOR swizzle (chunk g of row r at g^(r&7)) -> conflict-free frags.
template<bool RELU, bool WVT, bool SK>
__global__ __launch_bounds__(256) void gemm_bt(
    const short* __restrict__ A, const short* __restrict__ Bw,
    const float* __restrict__ bias,
    short* __restrict__ Cb, short* __restrict__ VTp,
    int M, int N, int K, int Ksp)
{
    __shared__ union U {
        struct { short As[128 * 64]; short Bs[128 * 64]; } s;
        short Cs[128 * 136];
    } u;   // 34,816 B -> 4 blocks/CU (LDS-limited)
    const int tid  = threadIdx.x;
    const int wave = tid >> 6, lane = tid & 63;
    const int m0 = blockIdx.x * 128, n0 = blockIdx.y * 128;
    const int wm = (wave & 1) * 64, wn = (wave >> 1) * 64;
    const int kbase = SK ? blockIdx.z * Ksp : 0;

    floatx4 acc[4][4];
#pragma unroll
    for (int i = 0; i < 4; ++i)
#pragma unroll
        for (int j = 0; j < 4; ++j) acc[i][j] = (floatx4){0.f, 0.f, 0.f, 0.f};

    const int srow = wave * 8 + (lane >> 3);
    const int scol = (((lane & 7) ^ ((lane >> 3) & 7))) * 8;
    const short* gA = A  + (size_t)(m0 + srow) * K + kbase + scol;
    const short* gB = Bw + (size_t)(n0 + srow) * K + kbase + scol;
    short* lA = u.s.As + wave * 512;
    short* lB = u.s.Bs + wave * 512;

    const int fr = lane & 15, quad = lane >> 4;
    const int kiters = (SK ? Ksp : K) >> 6;
    for (int kt = 0; kt < kiters; ++kt) {
#pragma unroll
        for (int s = 0; s < 4; ++s) {
            async_copy16(gA + (size_t)s * 32 * K, lA + s * 2048);
            async_copy16(gB + (size_t)s * 32 * K, lB + s * 2048);
        }
        gA += 64; gB += 64;
        __syncthreads();
#pragma unroll
        for (int ks = 0; ks < 2; ++ks) {
            short8 af[4], bf[4];
#pragma unroll
            for (int i = 0; i < 4; ++i) {
                int pos = ((ks * 4 + quad) ^ (fr & 7)) * 8;
                af[i] = *(const short8*)&u.s.As[(wm + i * 16 + fr) * 64 + pos];
                bf[i] = *(const short8*)&u.s.Bs[(wn + i * 16 + fr) * 64 + pos];
            }
#pragma unroll
            for (int i = 0; i < 4; ++i)
#pragma unroll
                for (int j = 0; j < 4; ++j)
                    acc[i][j] = __builtin_amdgcn_mfma_f32_16x16x32_bf16(af[i], bf[j], acc[i][j], 0, 0, 0);
        }
        __syncthreads();
    }

    const int cc = lane & 15;
    const int rb = (lane >> 4) * 4;
#pragma unroll
    for (int j = 0; j < 4; ++j) {
        int col = wn + j * 16 + cc;
        float bv = SK ? 0.0f : bias[n0 + col];
#pragma unroll
        for (int i = 0; i < 4; ++i) {
            int row = wm + i * 16 + rb;
#pragma unroll
            for (int r = 0; r < 4; ++r) {
                float v = acc[i][j][r] + bv;
                if (RELU) v = fmaxf(v, 0.0f);
                u.Cs[(row + r) * 136 + col] = f2bf(v);
            }
        }
    }
    __syncthreads();
    short* Co = Cb + (SK ? (size_t)blockIdx.z * PSTR : 0);
    const int trow = tid >> 4, tcol = (tid & 15) * 8;
#pragma unroll
    for (int p = 0; p < 8; ++p) {
        int row = p * 16 + trow;
        short8 vv = *(const short8*)&u.Cs[row * 136 + tcol];
        *(short8*)&Co[(size_t)(m0 + row) * N + n0 + tcol] = vv;
        if (WVT) {
            int gc0 = n0 + tcol;
            if (gc0 >= 2048) {
                int tok = m0 + row;
                int hc = (gc0 - 2048) >> 6, d0 = (gc0 - 2048) & 63;
                short* vrow = VTp + ((size_t)((tok >> 10) * 16 + hc) * 64 + d0) * 1024 + (tok & 1023);
#pragma unroll
                for (int e = 0; e < 8; ++e) vrow[(size_t)e * 1024] = vv[e];
            }
        }
    }
}

// ---------------------------------------------------------------- LayerNorm
__global__ __launch_bounds__(256) void ln_kernel(
    const float* __restrict__ xa, const short* __restrict__ parts, int nparts,
    const float* __restrict__ bias,
    const float* __restrict__ g, const float* __restrict__ beta,
    float* __restrict__ outf, short* __restrict__ outb)
{
    const int row = blockIdx.x;
    const int tid = threadIdx.x;
    float4 va = ((const float4*)(xa + (size_t)row * EE))[tid];
    float4 vb = ((const float4*)bias)[tid];
    float v0 = va.x + vb.x, v1 = va.y + vb.y, v2 = va.z + vb.z, v3 = va.w + vb.w;
#pragma unroll 4
    for (int p = 0; p < nparts; ++p) {
        unsigned long long u8 = ((const unsigned long long*)(parts + p * PSTR + (size_t)row * EE))[tid];
        v0 += bf2f((short)(u8 & 0xffff));
        v1 += bf2f((short)((u8 >> 16) & 0xffff));
        v2 += bf2f((short)((u8 >> 32) & 0xffff));
        v3 += bf2f((short)(u8 >> 48));
    }
    float s  = v0 + v1 + v2 + v3;
    float ss = v0 * v0 + v1 * v1 + v2 * v2 + v3 * v3;
#pragma unroll
    for (int o = 1; o < 64; o <<= 1) { s += __shfl_xor(s, o); ss += __shfl_xor(ss, o); }
    __shared__ float red[8];
    if ((tid & 63) == 0) { red[(tid >> 6) * 2] = s; red[(tid >> 6) * 2 + 1] = ss; }
    __syncthreads();
    s  = red[0] + red[2] + red[4] + red[6];
    ss = red[1] + red[3] + red[5] + red[7];
    float mean = s * (1.0f / EE);
    float var  = ss * (1.0f / EE) - mean * mean;
    float rstd = rsqrtf(var + 1e-5f);
    float4 vg = ((const float4*)g)[tid];
    float4 vt = ((const float4*)beta)[tid];
    float o0 = (v0 - mean) * rstd * vg.x + vt.x;
    float o1 = (v1 - mean) * rstd * vg.y + vt.y;
    float o2 = (v2 - mean) * rstd * vg.z + vt.z;
    float o3 = (v3 - mean) * rstd * vg.w + vt.w;
    if (outf) ((float4*)(outf + (size_t)row * EE))[tid] = make_float4(o0, o1, o2, o3);
    if (outb) {
        unsigned long long u =
              (unsigned long long)(unsigned short)f2bf(o0)
            | ((unsigned long long)(unsigned short)f2bf(o1) << 16)
            | ((unsigned long long)(unsigned short)f2bf(o2) << 32)
            | ((unsigned long long)(unsigned short)f2bf(o3) << 48);
        ((unsigned long long*)(outb + (size_t)row * EE))[tid] = u;
    }
}

// ---------------------------------------------------------------- attention (MFMA, register softmax)
// 512 thr / 8 waves; block = (i-tile 32, h, b) via flat id (i0 slow for L2).
// QK: wave = (mt = w>>2, quarter = w&3). Row softmax: quad shuffles + 1KB LDS.
// P -> Pl (XOR-swizzled). PV from Pl. NO scalar global stores: pb written as
// bulk short8 copy of Pl (un-swizzled) to pb[b][i][h][320]; ctx staged in LDS
// (aliases Pl) then short8 rows.
__global__ __launch_bounds__(512, 8) void attn_mfma(
    const short* __restrict__ qkv,
    const short* __restrict__ vt,
    short* __restrict__ ctxp,
    short* __restrict__ pb)     // [b][i][h][320] bf16
{
    __shared__ short Pl[32 * 320];   // 20,480 B (later reused as ctx tile)
    __shared__ float Red[4][2][32];  //  1,024 B
    const int tid = threadIdx.x, wave = tid >> 6, lane = tid & 63;
    const int quad = lane >> 4, mcol = lane & 15;
    const int id = blockIdx.x;
    const int i0 = (id >> 6) * 32, h = id & 15, b = (id >> 4) & 3;
    const int jb0 = i0 - 128;

    const short* qb = qkv + (size_t)(b * 1024) * 3072 + h * 64;
    const short* kb = qb + 1024;

    // ---- QK^T ----
    const int mt = wave >> 2, qtr = wave & 3;
    const short* qrow = qb + (size_t)(i0 + mt * 16 + mcol) * 3072 + quad * 8;
    short8 aq0 = *(const short8*)qrow;
    short8 aq1 = *(const short8*)(qrow + 32);

    floatx4 sacc[5];
#pragma unroll
    for (int c = 0; c < 5; ++c) sacc[c] = (floatx4){0.f, 0.f, 0.f, 0.f};
#pragma unroll
    for (int c = 0; c < 5; ++c) {
        int j = jb0 + (qtr * 5 + c) * 16 + mcol;
        j = min(max(j, 0), 1023);
        const short* kr = kb + (size_t)j * 3072 + quad * 8;
        short8 b0 = *(const short8*)kr;
        short8 b1 = *(const short8*)(kr + 32);
        sacc[c] = __builtin_amdgcn_mfma_f32_16x16x32_bf16(aq0, b0, sacc[c], 0, 0, 0);
        sacc[c] = __builtin_amdgcn_mfma_f32_16x16x32_bf16(aq1, b1, sacc[c], 0, 0, 0);
    }

    // ---- mask+scale, quarter row-max (quad shuffles) ----
    const int row0 = mt * 16 + quad * 4;
#pragma unroll
    for (int r = 0; r < 4; ++r) {
        int row = row0 + r;
        float m = -1e30f;
#pragma unroll
        for (int c = 0; c < 5; ++c) {
            int jo = (qtr * 5 + c) * 16 + mcol;
            bool val = (jo >= row) && (jo <= row + 256) && ((unsigned)(jb0 + jo) < 1024u);
            float s = val ? sacc[c][r] * 0.125f : -1e30f;
            sacc[c][r] = s;
            m = fmaxf(m, s);
        }
        m = fmaxf(m, __shfl_xor(m, 1));
        m = fmaxf(m, __shfl_xor(m, 2));
        m = fmaxf(m, __shfl_xor(m, 4));
        m = fmaxf(m, __shfl_xor(m, 8));
        if (mcol == 0) Red[qtr][0][row] = m;
    }
    __syncthreads();
    // ---- exp + quarter row-sum ----
#pragma unroll
    for (int r = 0; r < 4; ++r) {
        int row = row0 + r;
        float M = fmaxf(fmaxf(Red[0][0][row], Red[1][0][row]),
                        fmaxf(Red[2][0][row], Red[3][0][row]));
        float l = 0.f;
#pragma unroll
        for (int c = 0; c < 5; ++c) {
            float p = __expf(sacc[c][r] - M);
            sacc[c][r] = p;
            l += p;
        }
        l += __shfl_xor(l, 1);
        l += __shfl_xor(l, 2);
        l += __shfl_xor(l, 4);
        l += __shfl_xor(l, 8);
        if (mcol == 0) Red[qtr][1][row] = l;
    }
    __syncthreads();
    // ---- normalize, write P to swizzled LDS only ----
#pragma unroll
    for (int r = 0; r < 4; ++r) {
        int row = row0 + r;
        float inv = 1.0f / (Red[0][1][row] + Red[1][1][row] +
                            Red[2][1][row] + Red[3][1][row]);
#pragma unroll
        for (int c = 0; c < 5; ++c) {
            int jo = (qtr * 5 + c) * 16 + mcol;
            Pl[row * 320 + (((jo >> 3) ^ (row & 7)) * 8) + (jo & 7)] = f2bf(sacc[c][r] * inv);
        }
    }
    __syncthreads();

    // ---- PV (reads Pl) ----
    const int pmt = wave & 1, dt = wave >> 1;   // dt 0..3
    floatx4 cacc = (floatx4){0.f, 0.f, 0.f, 0.f};
    const short* vrow = vt + ((size_t)((b * 16 + h) * 64) + dt * 16 + mcol) * 1024;
    const int prow = (pmt * 16 + mcol) * 320;
#pragma unroll
    for (int jc = 0; jc < 10; ++jc) {
        short8 ap = *(const short8*)&Pl[prow + (((jc * 4 + quad) ^ (mcol & 7)) * 8)];
        int jg = jb0 + jc * 32 + quad * 8;
        if ((unsigned)jg >= 1024u) jg = 0;    // fully-masked frag (P=0)
        short8 bv = *(const short8*)(vrow + jg);
        cacc = __builtin_amdgcn_mfma_f32_16x16x32_bf16(ap, bv, cacc, 0, 0, 0);
    }

    // ---- bulk P copy: Pl (un-swizzle) -> pb[b][i0+row][h][0..320) ----
    short* pbb = pb + ((size_t)(b * 1024 + i0) * 16 + h) * 320;
    for (int t = tid; t < 1280; t += 512) {
        int row = t / 40, c = t - row * 40;
        short8 v = *(const short8*)&Pl[row * 320 + ((c ^ (row & 7)) * 8)];
        *(short8*)&pbb[(size_t)row * (16 * 320) + c * 8] = v;
    }
    __syncthreads();   // all Pl reads (PV frags + copy) complete

    // ---- ctx tile: regs -> LDS (stride 72, aliases Pl) -> coalesced rows ----
    short* Ct = Pl;
    const int colc = dt * 16 + mcol;
#pragma unroll
    for (int r = 0; r < 4; ++r)
        Ct[(pmt * 16 + quad * 4 + r) * 72 + colc] = f2bf(cacc[r]);
    __syncthreads();
    short* cb = ctxp + (size_t)(b * 1024 + i0) * 1024 + h * 64;
    for (int t = tid; t < 256; t += 512) {
        int row = t >> 3, c = t & 7;
        short8 v = *(const short8*)&Ct[row * 72 + c * 8];
        *(short8*)&cb[(size_t)row * 1024 + c * 8] = v;
    }
}

// ---------------------------------------------------------------- head-mean reduce
// attnW[b][i][j] = mean_h pb[b][i][h][j - (i&~31) + 128]
__global__ __launch_bounds__(256) void pb_reduce(const short* __restrict__ pb,
                                                 float* __restrict__ aw)
{
    const int i = blockIdx.x & 1023, b = blockIdx.x >> 10;
    const int i0 = i & ~31;
    __shared__ short P[16 * 320];    // 10,240 B, fully contiguous in pb
    const short8* src = (const short8*)(pb + (size_t)(b * 1024 + i) * 16 * 320);
    for (int t = threadIdx.x; t < 16 * 320 / 8; t += 256)
        ((short8*)P)[t] = src[t];
    __syncthreads();
    float* row = aw + ((size_t)(b * 1024) + i) * 1024;
    for (int j = threadIdx.x; j < 1024; j += 256) {
        int jo = j - i0 + 128;
        float s = 0.f;
        if ((unsigned)jo < 320u) {
#pragma unroll
            for (int hh = 0; hh < 16; ++hh)
                s += bf2f(P[hh * 320 + jo]);
            s *= (1.0f / 16.0f);
        }
        row[j] = s;
    }
}

// ---------------------------------------------------------------- launch
extern "C" void kernel_launch(void* const* d_in, const int* in_sizes, int n_in,
                              void* d_out, int out_size, void* d_ws, size_t ws_size,
                              hipStream_t stream) {
    const float* x    = (const float*)d_in[0];
    const float* wqkv = (const float*)d_in[1];
    const float* bqkv = (const float*)d_in[2];
    const float* wo   = (const float*)d_in[3];
    const float* bo   = (const float*)d_in[4];
    const float* g1   = (const float*)d_in[5];
    const float* be1  = (const float*)d_in[6];
    const float* w1   = (const float*)d_in[7];
    const float* bb1  = (const float*)d_in[8];
    const float* w2   = (const float*)d_in[9];
    const float* bb2  = (const float*)d_in[10];
    const float* g2   = (const float*)d_in[11];
    const float* be2  = (const float*)d_in[12];

    char* ws = (char*)d_ws;
    size_t off = 0;
    auto take = [&](size_t bytes) {
        void* p = ws + off;
        off += (bytes + 255) & ~(size_t)255;
        return p;
    };
    short* xb     = (short*)take((size_t)4096 * 1024 * 2);
    short* wqkv_b = (short*)take((size_t)3072 * 1024 * 2);
    short* wo_b   = (short*)take((size_t)1024 * 1024 * 2);
    short* w1_b   = (short*)take((size_t)4096 * 1024 * 2);
    short* w2_b   = (short*)take((size_t)1024 * 4096 * 2);
    short* qkv_b  = (short*)take((size_t)4096 * 3072 * 2);
    short* ctx_b  = (short*)take((size_t)4096 * 1024 * 2);
    short* ff2_p  = qkv_b;                                      // FFN2 bf16 partials x4
    short* attn_p = (short*)take((size_t)2 * 4096 * 1024 * 2);  // out-proj bf16 partials x2
    float* h_f    = (float*)take((size_t)4096 * 1024 * 4);
    short* vt_ws  = (short*)h_f;                                // vt dead before ln1 writes h_f
    short* h_b    = (short*)take((size_t)4096 * 1024 * 2);
    short* pb_ws  = (short*)take((size_t)4 * 1024 * 16 * 320 * 2);  // 41.9 MB
    short* ff_b   = pb_ws;                                      // FFN1 out aliases pb (33.6 <= 41.9)

    float* out_f = (float*)d_out;
    float* attnW = (float*)d_out + (size_t)4 * 1024 * 1024;

    // bf16 conversions (single launch)
    cvt5<<<16384, 256, 0, stream>>>(x, wqkv, wo, w1, w2, xb, wqkv_b, wo_b, w1_b, w2_b);

    // qkv projection (also writes V transposed into vt_ws)
    gemm_bt<false, true, false><<<dim3(32, 24), 256, 0, stream>>>(
        xb, wqkv_b, bqkv, qkv_b, vt_ws, 4096, 3072, 1024, 1024);

    // banded attention (MFMA, register softmax); flat grid, i0 slow
    attn_mfma<<<2048, 512, 0, stream>>>(qkv_b, vt_ws, ctx_b, pb_ws);

    // head-mean attention weights
    pb_reduce<<<4096, 256, 0, stream>>>(pb_ws, attnW);

    // out projection, split-K=2 -> bf16 partials
    gemm_bt<false, false, true><<<dim3(32, 8, 2), 256, 0, stream>>>(
        ctx_b, wo_b, nullptr, attn_p, nullptr, 4096, 1024, 1024, 512);

    // h = LN(x + p0 + p1 + bo)
    ln_kernel<<<4096, 256, 0, stream>>>(x, attn_p, 2, bo, g1, be1, h_f, h_b);

    // FFN1 + ReLU -> bf16
    gemm_bt<true, false, false><<<dim3(32, 32), 256, 0, stream>>>(
        h_b, w1_b, bb1, ff_b, nullptr, 4096, 4096, 1024, 1024);

    // FFN2, split-K=4 -> bf16 partials
    gemm_bt<false, false, true><<<dim3(32, 8, 4), 256, 0, stream>>>(
        ff_b, w2_b, nullptr, ff2_p, nullptr, 4096, 1024, 4096, 1024);

    // out = LN(h + p0..p3 + bb2)
    ln_kernel<<<4096, 256, 0, stream>>>(h_f, ff2_p, 4, bb2, g2, be2, out_f, nullptr);
}

// Round 9
// 358.530 us; speedup vs baseline: 1.0870x; 1.0870x over previous
//
#include <hip/hip_runtime.h>

// Shapes fixed by setup_inputs(): B=4, L=1024, E=1024, H=16, D=64, W=128
#define BB 4
#define LL 1024
#define EE 1024
#define HH 16
#define DD 64

typedef __attribute__((ext_vector_type(8))) short short8;
typedef __attribute__((ext_vector_type(4))) float floatx4;

#define PSTR ((size_t)4096 * 1024)   // split-K partial stride (elements, bf16)

__device__ __forceinline__ float bf2f(short s) {
    union { unsigned u; float f; } c;
    c.u = ((unsigned)(unsigned short)s) << 16;
    return c.f;
}
__device__ __forceinline__ short f2bf(float f) {
    union { float f; unsigned u; } c; c.f = f;
    unsigned r = c.u + 0x7fffu + ((c.u >> 16) & 1u);
    return (short)(r >> 16);
}

__device__ __forceinline__ void async_copy16(const void* g, void* l) {
    __builtin_amdgcn_global_load_lds(
        (const __attribute__((address_space(1))) unsigned int*)g,
        (__attribute__((address_space(3))) unsigned int*)l, 16, 0, 0);
}

// ---------------------------------------------------------------- convert (all 5 tensors, one launch)
__global__ __launch_bounds__(256) void cvt5(
    const float* __restrict__ x, const float* __restrict__ wqkv,
    const float* __restrict__ wo, const float* __restrict__ w1,
    const float* __restrict__ w2,
    short* __restrict__ xb, short* __restrict__ wqkvb, short* __restrict__ wob,
    short* __restrict__ w1b, short* __restrict__ w2b)
{
    int bi = blockIdx.x;
    const float* in; short* out; int base;
    if      (bi <  4096) { in = x;    out = xb;    base = 0;     }
    else if (bi <  7168) { in = wqkv; out = wqkvb; base = 4096;  }
    else if (bi <  8192) { in = wo;   out = wob;   base = 7168;  }
    else if (bi < 12288) { in = w1;   out = w1b;   base = 8192;  }
    else                 { in = w2;   out = w2b;   base = 12288; }
    int i = (bi - base) * 256 + threadIdx.x;
    float4 v = ((const float4*)in)[i];
    unsigned long long u =
          (unsigned long long)(unsigned short)f2bf(v.x)
        | ((unsigned long long)(unsigned short)f2bf(v.y) << 16)
        | ((unsigned long long)(unsigned short)f2bf(v.z) << 32)
        | ((unsigned long long)(unsigned short)f2bf(v.w) << 48);
    ((unsigned long long*)out)[i] = u;
}

// ---------------------------------------------------------------- GEMM (NT)
// C[m,n] = sum_k A[m,k]*B[n,k] (+bias); 128x128 tile, BK=64, 256 thr.
// LDS k-chunk XOR swizzle (chunk g of row r at g^(r&7)) -> conflict-free frags.
template<bool RELU, bool WVT, bool SK>
__global__ __launch_bounds__(256) void gemm_bt(
    const short* __restrict__ A, const short* __restrict__ Bw,
    const float* __restrict__ bias,
    short* __restrict__ Cb, short* __restrict__ VTp,
    int M, int N, int K, int Ksp)
{
    __shared__ union U {
        struct { short As[128 * 64]; short Bs[128 * 64]; } s;
        short Cs[128 * 136];
    } u;   // 34,816 B -> 4 blocks/CU (LDS-limited)
    const int tid  = threadIdx.x;
    const int wave = tid >> 6, lane = tid & 63;
    const int m0 = blockIdx.x * 128, n0 = blockIdx.y * 128;
    const int wm = (wave & 1) * 64, wn = (wave >> 1) * 64;
    const int kbase = SK ? blockIdx.z * Ksp : 0;

    floatx4 acc[4][4];
#pragma unroll
    for (int i = 0; i < 4; ++i)
#pragma unroll
        for (int j = 0; j < 4; ++j) acc[i][j] = (floatx4){0.f, 0.f, 0.f, 0.f};

    const int srow = wave * 8 + (lane >> 3);
    const int scol = (((lane & 7) ^ ((lane >> 3) & 7))) * 8;
    const short* gA = A  + (size_t)(m0 + srow) * K + kbase + scol;
    const short* gB = Bw + (size_t)(n0 + srow) * K + kbase + scol;
    short* lA = u.s.As + wave * 512;
    short* lB = u.s.Bs + wave * 512;

    const int fr = lane & 15, quad = lane >> 4;
    const int kiters = (SK ? Ksp : K) >> 6;
    for (int kt = 0; kt < kiters; ++kt) {
#pragma unroll
        for (int s = 0; s < 4; ++s) {
            async_copy16(gA + (size_t)s * 32 * K, lA + s * 2048);
            async_copy16(gB + (size_t)s * 32 * K, lB + s * 2048);
        }
        gA += 64; gB += 64;
        __syncthreads();
#pragma unroll
        for (int ks = 0; ks < 2; ++ks) {
            short8 af[4], bf[4];
#pragma unroll
            for (int i = 0; i < 4; ++i) {
                int pos = ((ks * 4 + quad) ^ (fr & 7)) * 8;
                af[i] = *(const short8*)&u.s.As[(wm + i * 16 + fr) * 64 + pos];
                bf[i] = *(const short8*)&u.s.Bs[(wn + i * 16 + fr) * 64 + pos];
            }
#pragma unroll
            for (int i = 0; i < 4; ++i)
#pragma unroll
                for (int j = 0; j < 4; ++j)
                    acc[i][j] = __builtin_amdgcn_mfma_f32_16x16x32_bf16(af[i], bf[j], acc[i][j], 0, 0, 0);
        }
        __syncthreads();
    }

    const int cc = lane & 15;
    const int rb = (lane >> 4) * 4;
#pragma unroll
    for (int j = 0; j < 4; ++j) {
        int col = wn + j * 16 + cc;
        float bv = SK ? 0.0f : bias[n0 + col];
#pragma unroll
        for (int i = 0; i < 4; ++i) {
            int row = wm + i * 16 + rb;
#pragma unroll
            for (int r = 0; r < 4; ++r) {
                float v = acc[i][j][r] + bv;
                if (RELU) v = fmaxf(v, 0.0f);
                u.Cs[(row + r) * 136 + col] = f2bf(v);
            }
        }
    }
    __syncthreads();
    short* Co = Cb + (SK ? (size_t)blockIdx.z * PSTR : 0);
    const int trow = tid >> 4, tcol = (tid & 15) * 8;
#pragma unroll
    for (int p = 0; p < 8; ++p) {
        int row = p * 16 + trow;
        short8 vv = *(const short8*)&u.Cs[row * 136 + tcol];
        *(short8*)&Co[(size_t)(m0 + row) * N + n0 + tcol] = vv;
        if (WVT) {
            int gc0 = n0 + tcol;
            if (gc0 >= 2048) {
                int tok = m0 + row;
                int hc = (gc0 - 2048) >> 6, d0 = (gc0 - 2048) & 63;
                short* vrow = VTp + ((size_t)((tok >> 10) * 16 + hc) * 64 + d0) * 1024 + (tok & 1023);
#pragma unroll
                for (int e = 0; e < 8; ++e) vrow[(size_t)e * 1024] = vv[e];
            }
        }
    }
}

// ---------------------------------------------------------------- LayerNorm
__global__ __launch_bounds__(256) void ln_kernel(
    const float* __restrict__ xa, const short* __restrict__ parts, int nparts,
    const float* __restrict__ bias,
    const float* __restrict__ g, const float* __restrict__ beta,
    float* __restrict__ outf, short* __restrict__ outb)
{
    const int row = blockIdx.x;
    const int tid = threadIdx.x;
    float4 va = ((const float4*)(xa + (size_t)row * EE))[tid];
    float4 vb = ((const float4*)bias)[tid];
    float v0 = va.x + vb.x, v1 = va.y + vb.y, v2 = va.z + vb.z, v3 = va.w + vb.w;
#pragma unroll 4
    for (int p = 0; p < nparts; ++p) {
        unsigned long long u8 = ((const unsigned long long*)(parts + p * PSTR + (size_t)row * EE))[tid];
        v0 += bf2f((short)(u8 & 0xffff));
        v1 += bf2f((short)((u8 >> 16) & 0xffff));
        v2 += bf2f((short)((u8 >> 32) & 0xffff));
        v3 += bf2f((short)(u8 >> 48));
    }
    float s  = v0 + v1 + v2 + v3;
    float ss = v0 * v0 + v1 * v1 + v2 * v2 + v3 * v3;
#pragma unroll
    for (int o = 1; o < 64; o <<= 1) { s += __shfl_xor(s, o); ss += __shfl_xor(ss, o); }
    __shared__ float red[8];
    if ((tid & 63) == 0) { red[(tid >> 6) * 2] = s; red[(tid >> 6) * 2 + 1] = ss; }
    __syncthreads();
    s  = red[0] + red[2] + red[4] + red[6];
    ss = red[1] + red[3] + red[5] + red[7];
    float mean = s * (1.0f / EE);
    float var  = ss * (1.0f / EE) - mean * mean;
    float rstd = rsqrtf(var + 1e-5f);
    float4 vg = ((const float4*)g)[tid];
    float4 vt = ((const float4*)beta)[tid];
    float o0 = (v0 - mean) * rstd * vg.x + vt.x;
    float o1 = (v1 - mean) * rstd * vg.y + vt.y;
    float o2 = (v2 - mean) * rstd * vg.z + vt.z;
    float o3 = (v3 - mean) * rstd * vg.w + vt.w;
    if (outf) ((float4*)(outf + (size_t)row * EE))[tid] = make_float4(o0, o1, o2, o3);
    if (outb) {
        unsigned long long u =
              (unsigned long long)(unsigned short)f2bf(o0)
            | ((unsigned long long)(unsigned short)f2bf(o1) << 16)
            | ((unsigned long long)(unsigned short)f2bf(o2) << 32)
            | ((unsigned long long)(unsigned short)f2bf(o3) << 48);
        ((unsigned long long*)(outb + (size_t)row * EE))[tid] = u;
    }
}

// ---------------------------------------------------------------- attention (MFMA, register softmax)
// 512 thr / 8 waves; block = (i-tile 32, h, b) via flat id (i0 slow for L2).
// QK: wave = (mt = w>>2, quarter = w&3). Row softmax: quad shuffles + 1KB LDS.
// P -> Pl (XOR-swizzled). PV from Pl.
// pb layout [b][h][i][320]: each block writes ONE private contiguous 20,480-B
// region (no cache-line sharing between blocks / XCDs -> no RMW or write amp).
__global__ __launch_bounds__(512, 8) void attn_mfma(
    const short* __restrict__ qkv,
    const short* __restrict__ vt,
    short* __restrict__ ctxp,
    short* __restrict__ pb)     // [b][h][i][320] bf16
{
    __shared__ short Pl[32 * 320];   // 20,480 B (later reused as ctx tile)
    __shared__ float Red[4][2][32];  //  1,024 B
    const int tid = threadIdx.x, wave = tid >> 6, lane = tid & 63;
    const int quad = lane >> 4, mcol = lane & 15;
    const int id = blockIdx.x;
    const int i0 = (id >> 6) * 32, h = id & 15, b = (id >> 4) & 3;
    const int jb0 = i0 - 128;

    const short* qb = qkv + (size_t)(b * 1024) * 3072 + h * 64;
    const short* kb = qb + 1024;

    // ---- QK^T ----
    const int mt = wave >> 2, qtr = wave & 3;
    const short* qrow = qb + (size_t)(i0 + mt * 16 + mcol) * 3072 + quad * 8;
    short8 aq0 = *(const short8*)qrow;
    short8 aq1 = *(const short8*)(qrow + 32);

    floatx4 sacc[5];
#pragma unroll
    for (int c = 0; c < 5; ++c) sacc[c] = (floatx4){0.f, 0.f, 0.f, 0.f};
#pragma unroll
    for (int c = 0; c < 5; ++c) {
        int j = jb0 + (qtr * 5 + c) * 16 + mcol;
        j = min(max(j, 0), 1023);
        const short* kr = kb + (size_t)j * 3072 + quad * 8;
        short8 b0 = *(const short8*)kr;
        short8 b1 = *(const short8*)(kr + 32);
        sacc[c] = __builtin_amdgcn_mfma_f32_16x16x32_bf16(aq0, b0, sacc[c], 0, 0, 0);
        sacc[c] = __builtin_amdgcn_mfma_f32_16x16x32_bf16(aq1, b1, sacc[c], 0, 0, 0);
    }

    // ---- mask+scale, quarter row-max (quad shuffles) ----
    const int row0 = mt * 16 + quad * 4;
#pragma unroll
    for (int r = 0; r < 4; ++r) {
        int row = row0 + r;
        float m = -1e30f;
#pragma unroll
        for (int c = 0; c < 5; ++c) {
            int jo = (qtr * 5 + c) * 16 + mcol;
            bool val = (jo >= row) && (jo <= row + 256) && ((unsigned)(jb0 + jo) < 1024u);
            float s = val ? sacc[c][r] * 0.125f : -1e30f;
            sacc[c][r] = s;
            m = fmaxf(m, s);
        }
        m = fmaxf(m, __shfl_xor(m, 1));
        m = fmaxf(m, __shfl_xor(m, 2));
        m = fmaxf(m, __shfl_xor(m, 4));
        m = fmaxf(m, __shfl_xor(m, 8));
        if (mcol == 0) Red[qtr][0][row] = m;
    }
    __syncthreads();
    // ---- exp + quarter row-sum ----
#pragma unroll
    for (int r = 0; r < 4; ++r) {
        int row = row0 + r;
        float M = fmaxf(fmaxf(Red[0][0][row], Red[1][0][row]),
                        fmaxf(Red[2][0][row], Red[3][0][row]));
        float l = 0.f;
#pragma unroll
        for (int c = 0; c < 5; ++c) {
            float p = __expf(sacc[c][r] - M);
            sacc[c][r] = p;
            l += p;
        }
        l += __shfl_xor(l, 1);
        l += __shfl_xor(l, 2);
        l += __shfl_xor(l, 4);
        l += __shfl_xor(l, 8);
        if (mcol == 0) Red[qtr][1][row] = l;
    }
    __syncthreads();
    // ---- normalize, write P to swizzled LDS only ----
#pragma unroll
    for (int r = 0; r < 4; ++r) {
        int row = row0 + r;
        float inv = 1.0f / (Red[0][1][row] + Red[1][1][row] +
                            Red[2][1][row] + Red[3][1][row]);
#pragma unroll
        for (int c = 0; c < 5; ++c) {
            int jo = (qtr * 5 + c) * 16 + mcol;
            Pl[row * 320 + (((jo >> 3) ^ (row & 7)) * 8) + (jo & 7)] = f2bf(sacc[c][r] * inv);
        }
    }
    __syncthreads();

    // ---- PV (reads Pl) ----
    const int pmt = wave & 1, dt = wave >> 1;   // dt 0..3
    floatx4 cacc = (floatx4){0.f, 0.f, 0.f, 0.f};
    const short* vrow = vt + ((size_t)((b * 16 + h) * 64) + dt * 16 + mcol) * 1024;
    const int prow = (pmt * 16 + mcol) * 320;
#pragma unroll
    for (int jc = 0; jc < 10; ++jc) {
        short8 ap = *(const short8*)&Pl[prow + (((jc * 4 + quad) ^ (mcol & 7)) * 8)];
        int jg = jb0 + jc * 32 + quad * 8;
        if ((unsigned)jg >= 1024u) jg = 0;    // fully-masked frag (P=0)
        short8 bv = *(const short8*)(vrow + jg);
        cacc = __builtin_amdgcn_mfma_f32_16x16x32_bf16(ap, bv, cacc, 0, 0, 0);
    }

    // ---- bulk P copy: Pl (un-swizzle) -> private pb region (contiguous) ----
    short* pbb = pb + ((size_t)((b * 16 + h) * 1024) + i0) * 320;
    for (int t = tid; t < 1280; t += 512) {
        int row = t / 40, c = t - row * 40;
        short8 v = *(const short8*)&Pl[row * 320 + ((c ^ (row & 7)) * 8)];
        *(short8*)&pbb[(size_t)t * 8] = v;     // t*8 == row*320 + c*8
    }
    __syncthreads();   // all Pl reads (PV frags + copy) complete

    // ---- ctx tile: regs -> LDS (stride 72, aliases Pl) -> coalesced rows ----
    short* Ct = Pl;
    const int colc = dt * 16 + mcol;
#pragma unroll
    for (int r = 0; r < 4; ++r)
        Ct[(pmt * 16 + quad * 4 + r) * 72 + colc] = f2bf(cacc[r]);
    __syncthreads();
    short* cb = ctxp + (size_t)(b * 1024 + i0) * 1024 + h * 64;
    for (int t = tid; t < 256; t += 512) {
        int row = t >> 3, c = t & 7;
        short8 v = *(const short8*)&Ct[row * 72 + c * 8];
        *(short8*)&cb[(size_t)row * 1024 + c * 8] = v;
    }
}

// ---------------------------------------------------------------- head-mean reduce
// attnW[b][i][j] = mean_h pb[b][h][i][j - (i&~31) + 128]
__global__ __launch_bounds__(256) void pb_reduce(const short* __restrict__ pb,
                                                 float* __restrict__ aw)
{
    const int i = blockIdx.x & 1023, b = blockIdx.x >> 10;
    const int i0 = i & ~31;
    __shared__ short P[16 * 320];    // 10,240 B
    for (int t = threadIdx.x; t < 640; t += 256) {
        int hh = t / 40, c = t - hh * 40;
        ((short8*)P)[t] = *(const short8*)(pb +
            ((size_t)((b * 16 + hh) * 1024) + i) * 320 + c * 8);
    }
    __syncthreads();
    float* row = aw + ((size_t)(b * 1024) + i) * 1024;
    for (int j = threadIdx.x; j < 1024; j += 256) {
        int jo = j - i0 + 128;
        float s = 0.f;
        if ((unsigned)jo < 320u) {
#pragma unroll
            for (int hh = 0; hh < 16; ++hh)
                s += bf2f(P[hh * 320 + jo]);
            s *= (1.0f / 16.0f);
        }
        row[j] = s;
    }
}

// ---------------------------------------------------------------- launch
extern "C" void kernel_launch(void* const* d_in, const int* in_sizes, int n_in,
                              void* d_out, int out_size, void* d_ws, size_t ws_size,
                              hipStream_t stream) {
    const float* x    = (const float*)d_in[0];
    const float* wqkv = (const float*)d_in[1];
    const float* bqkv = (const float*)d_in[2];
    const float* wo   = (const float*)d_in[3];
    const float* bo   = (const float*)d_in[4];
    const float* g1   = (const float*)d_in[5];
    const float* be1  = (const float*)d_in[6];
    const float* w1   = (const float*)d_in[7];
    const float* bb1  = (const float*)d_in[8];
    const float* w2   = (const float*)d_in[9];
    const float* bb2  = (const float*)d_in[10];
    const float* g2   = (const float*)d_in[11];
    const float* be2  = (const float*)d_in[12];

    char* ws = (char*)d_ws;
    size_t off = 0;
    auto take = [&](size_t bytes) {
        void* p = ws + off;
        off += (bytes + 255) & ~(size_t)255;
        return p;
    };
    short* xb     = (short*)take((size_t)4096 * 1024 * 2);
    short* wqkv_b = (short*)take((size_t)3072 * 1024 * 2);
    short* wo_b   = (short*)take((size_t)1024 * 1024 * 2);
    short* w1_b   = (short*)take((size_t)4096 * 1024 * 2);
    short* w2_b   = (short*)take((size_t)1024 * 4096 * 2);
    short* qkv_b  = (short*)take((size_t)4096 * 3072 * 2);
    short* ctx_b  = (short*)take((size_t)4096 * 1024 * 2);
    short* ff2_p  = qkv_b;                                      // FFN2 bf16 partials x4
    short* attn_p = (short*)take((size_t)2 * 4096 * 1024 * 2);  // out-proj bf16 partials x2
    float* h_f    = (float*)take((size_t)4096 * 1024 * 4);
    short* vt_ws  = (short*)h_f;                                // vt dead before ln1 writes h_f
    short* h_b    = (short*)take((size_t)4096 * 1024 * 2);
    short* pb_ws  = (short*)take((size_t)4 * 16 * 1024 * 320 * 2);  // 41.9 MB
    short* ff_b   = pb_ws;                                      // FFN1 out aliases pb (33.6 <= 41.9)

    float* out_f = (float*)d_out;
    float* attnW = (float*)d_out + (size_t)4 * 1024 * 1024;

    // bf16 conversions (single launch)
    cvt5<<<16384, 256, 0, stream>>>(x, wqkv, wo, w1, w2, xb, wqkv_b, wo_b, w1_b, w2_b);

    // qkv projection (also writes V transposed into vt_ws)
    gemm_bt<false, true, false><<<dim3(32, 24), 256, 0, stream>>>(
        xb, wqkv_b, bqkv, qkv_b, vt_ws, 4096, 3072, 1024, 1024);

    // banded attention (MFMA, register softmax); flat grid, i0 slow
    attn_mfma<<<2048, 512, 0, stream>>>(qkv_b, vt_ws, ctx_b, pb_ws);

    // head-mean attention weights
    pb_reduce<<<4096, 256, 0, stream>>>(pb_ws, attnW);

    // out projection, split-K=2 -> bf16 partials
    gemm_bt<false, false, true><<<dim3(32, 8, 2), 256, 0, stream>>>(
        ctx_b, wo_b, nullptr, attn_p, nullptr, 4096, 1024, 1024, 512);

    // h = LN(x + p0 + p1 + bo)
    ln_kernel<<<4096, 256, 0, stream>>>(x, attn_p, 2, bo, g1, be1, h_f, h_b);

    // FFN1 + ReLU -> bf16
    gemm_bt<true, false, false><<<dim3(32, 32), 256, 0, stream>>>(
        h_b, w1_b, bb1, ff_b, nullptr, 4096, 4096, 1024, 1024);

    // FFN2, split-K=4 -> bf16 partials
    gemm_bt<false, false, true><<<dim3(32, 8, 4), 256, 0, stream>>>(
        ff_b, w2_b, nullptr, ff2_p, nullptr, 4096, 1024, 4096, 1024);

    // out = LN(h + p0..p3 + bb2)
    ln_kernel<<<4096, 256, 0, stream>>>(h_f, ff2_p, 4, bb2, g2, be2, out_f, nullptr);
}